// Round 7
// baseline (321.512 us; speedup 1.0000x reference)
//
#include <hip/hip_runtime.h>

typedef unsigned short u16;
typedef __attribute__((ext_vector_type(4))) float floatx4;
typedef __attribute__((ext_vector_type(8))) short short8;

#define MAXROWS 5120   // 4096 slots + 8*128 padding
#define MAXMT 40

__device__ __forceinline__ u16 f2bf(float f) {
    union { float f; unsigned u; } v; v.f = f;
    unsigned r = v.u + 0x7FFF + ((v.u >> 16) & 1);
    return (u16)(r >> 16);
}
__device__ __forceinline__ float bf2f(u16 h) {
    union { unsigned u; float f; } v; v.u = ((unsigned)h) << 16; return v.f;
}
__device__ __forceinline__ float silu_f(float x) { return x / (1.f + __expf(-x)); }

__device__ __forceinline__ void gl_lds16(const void* g, void* l) {
    __builtin_amdgcn_global_load_lds(
        (__attribute__((address_space(1))) unsigned int*)g,
        (__attribute__((address_space(3))) unsigned int*)l, 16, 0, 0);
}

// ---- fused: gate (blocks 0..511) + fp32->bf16 conversion ----
// S12 layout: 32-row groups: rows g*32+0..15 = sw1[g*16..], g*32+16..31 = sw2[g*16..]
__global__ void conv_gate(const float* __restrict__ w1, const float* __restrict__ w2,
                          const float* __restrict__ w3, const float* __restrict__ sw1,
                          const float* __restrict__ sw2, const float* __restrict__ sw3,
                          const float* __restrict__ x, const float* __restrict__ gw,
                          u16* __restrict__ W13, u16* __restrict__ W2b,
                          u16* __restrict__ S12, u16* __restrict__ S3b,
                          u16* __restrict__ Xb,
                          int* __restrict__ idxA, float* __restrict__ wA) {
    int bid = blockIdx.x;
    if (bid < 512) {  // ---- gate ----
        int w = threadIdx.x >> 6, lane = threadIdx.x & 63;
        int t = bid * 4 + w;
        const float* xr = x + (size_t)t * 1024;
        float acc[8];
#pragma unroll
        for (int e = 0; e < 8; e++) acc[e] = 0.f;
#pragma unroll
        for (int i = 0; i < 16; i++) {
            float xv = xr[lane + (i << 6)];
#pragma unroll
            for (int e = 0; e < 8; e++) acc[e] += xv * gw[e * 1024 + lane + (i << 6)];
        }
#pragma unroll
        for (int e = 0; e < 8; e++)
            for (int off = 32; off > 0; off >>= 1) acc[e] += __shfl_xor(acc[e], off);
        if (lane == 0) {
            float m = acc[0];
#pragma unroll
            for (int e = 1; e < 8; e++) m = fmaxf(m, acc[e]);
            float p[8], s = 0.f;
#pragma unroll
            for (int e = 0; e < 8; e++) { p[e] = __expf(acc[e] - m); s += p[e]; }
            float inv = 1.f / s;
#pragma unroll
            for (int e = 0; e < 8; e++) p[e] *= inv;
            int i0 = 0;
#pragma unroll
            for (int e = 1; e < 8; e++) if (p[e] > p[i0]) i0 = e;
            int i1 = (i0 == 0) ? 1 : 0;
            for (int e = i1 + 1; e < 8; e++) if (e != i0 && p[e] > p[i1]) i1 = e;
            idxA[2 * t] = i0; idxA[2 * t + 1] = i1;
            wA[2 * t] = p[i0]; wA[2 * t + 1] = p[i1];
        }
        return;
    }
    long j = (long)(bid - 512) * 256 + threadIdx.x;
    const float* src; u16* dst; long d;
    if (j < 2097152) {
        long e = j >> 18; src = w1; dst = W13; d = j + (e << 18);
    } else if ((j -= 2097152) < 2097152) {
        long e = j >> 18; src = w3; dst = W13; d = j + (e << 18) + 262144;
    } else if ((j -= 2097152) < 2097152) { src = w2;  dst = W2b; d = j; }
    else if ((j -= 2097152) < 524288) {
        long rr = j >> 8, c4 = j & 255;
        long br = ((rr >> 4) << 5) + (rr & 15);
        src = sw1; dst = S12; d = (br << 8) + c4;
    } else if ((j -= 524288) < 524288) {
        long rr = j >> 8, c4 = j & 255;
        long br = ((rr >> 4) << 5) + 16 + (rr & 15);
        src = sw2; dst = S12; d = (br << 8) + c4;
    } else if ((j -= 524288) < 524288)     { src = sw3; dst = S3b; d = j; }
    else { j -= 524288; src = x; dst = Xb; d = j; }
    float4 v = ((const float4*)src)[j];
    ushort4 o; o.x = f2bf(v.x); o.y = f2bf(v.y); o.z = f2bf(v.z); o.w = f2bf(v.w);
    ((ushort4*)dst)[d] = o;
}

// ---- single-wave deterministic rank/scatter (0 atomics) ----
__global__ void rank_k(const int* __restrict__ idxA, int* __restrict__ tileexp,
                       int* __restrict__ ntiles, int* __restrict__ slot_of) {
    int lane = threadIdx.x;
    const int* my = idxA + lane * 64;
    int h[8];
#pragma unroll
    for (int e = 0; e < 8; e++) h[e] = 0;
    for (int i = 0; i < 64; i++) {
        int v = my[i];
#pragma unroll
        for (int e = 0; e < 8; e++) h[e] += (v == e);
    }
    int excl[8], tot[8];
#pragma unroll
    for (int e = 0; e < 8; e++) {
        int inc = h[e];
        for (int off = 1; off < 64; off <<= 1) {
            int up = __shfl_up(inc, off);
            if (lane >= off) inc += up;
        }
        excl[e] = inc - h[e];
        tot[e] = __shfl(inc, 63);
    }
    int base[8], tiles = 0;
#pragma unroll
    for (int e = 0; e < 8; e++) {
        base[e] = tiles * 128;
        tiles += (tot[e] + 127) >> 7;
    }
    if (lane == 0) {
        ntiles[0] = tiles;
        int t = 0;
        for (int e = 0; e < 8; e++) {
            int te = (tot[e] + 127) >> 7;
            for (int j = 0; j < te; j++) tileexp[t++] = e;
        }
    }
    int c[8];
#pragma unroll
    for (int e = 0; e < 8; e++) c[e] = base[e] + excl[e];
    for (int i = 0; i < 64; i++) {
        int v = my[i], slot = 0;
#pragma unroll
        for (int e = 0; e < 8; e++) slot += (v == e) ? c[e] : 0;
#pragma unroll
        for (int e = 0; e < 8; e++) c[e] += (v == e);
        slot_of[lane * 64 + i] = slot;
    }
}

__global__ void build_xs(const float* __restrict__ x, const float* __restrict__ wA,
                         const int* __restrict__ slot_of, u16* __restrict__ XS) {
    int s = blockIdx.x, i = threadIdx.x;
    int t = s >> 1; float w = wA[s]; int slot = slot_of[s];
    float4 v = ((const float4*)(x + (size_t)t * 1024))[i];
    ushort4 o; o.x = f2bf(v.x * w); o.y = f2bf(v.y * w); o.z = f2bf(v.z * w); o.w = f2bf(v.w * w);
    ((ushort4*)(XS + (size_t)slot * 1024))[i] = o;
}

// ======== 512-thread 128x256-tile BK=64 GEMM core ========
// LDS (u16 idx): A rows [0,8192): row r at r*64, 8 granules of 8 elems.
//                B rows [8192,24576): row r at 8192 + r*64.
// Granule swizzle: LDS slot s of row r holds global granule s ^ (r & 7).
// Staging: 8 lanes/row (rloc=lane>>3, clds=lane&7), wave w: A rows [16w,16w+16),
// B rows [32w, 32w+32).  Waves: wm = w>>2 (2 m-halves), wn = w&3 (4 n-quarters).
#define STAGE(Ab, Bb, lda, kk)                                                 \
    {                                                                          \
        _Pragma("unroll")                                                      \
        for (int t = 0; t < 2; t++) {                                          \
            int r = (w << 4) + (t << 3) + rloc;                                \
            int cg = clds ^ (r & 7);                                           \
            gl_lds16(Ab + (size_t)(m0 + r) * (lda) + (kk) + (cg << 3),         \
                     &LDS[((w << 4) + (t << 3)) << 6]);                        \
        }                                                                      \
        _Pragma("unroll")                                                      \
        for (int t = 0; t < 4; t++) {                                          \
            int r = (w << 5) + (t << 3) + rloc;                                \
            int cg = clds ^ (r & 7);                                           \
            gl_lds16(Bb + (size_t)(n0 + r) * (lda) + (kk) + (cg << 3),         \
                     &LDS[8192 + (((w << 5) + (t << 3)) << 6)]);               \
        }                                                                      \
    }

#define COMPUTE()                                                              \
    {                                                                          \
        _Pragma("unroll")                                                      \
        for (int hh = 0; hh < 2; hh++) {                                       \
            short8 af[4], bf[4];                                               \
            _Pragma("unroll")                                                  \
            for (int i = 0; i < 4; i++) {                                      \
                int rr = (wm << 6) + (i << 4) + l15;                           \
                int sl = ((hh << 2) + q) ^ (rr & 7);                           \
                af[i] = *(const short8*)&LDS[(rr << 6) + (sl << 3)];           \
            }                                                                  \
            _Pragma("unroll")                                                  \
            for (int j = 0; j < 4; j++) {                                      \
                int rr = (wn << 6) + (j << 4) + l15;                           \
                int sl = ((hh << 2) + q) ^ (rr & 7);                           \
                bf[j] = *(const short8*)&LDS[8192 + (rr << 6) + (sl << 3)];    \
            }                                                                  \
            _Pragma("unroll")                                                  \
            for (int i = 0; i < 4; i++)                                        \
                _Pragma("unroll")                                              \
                for (int j = 0; j < 4; j++)                                    \
                    acc[i][j] = __builtin_amdgcn_mfma_f32_16x16x32_bf16(       \
                        af[i], bf[j], acc[i][j], 0, 0, 0);                     \
        }                                                                      \
    }

#define GEMM_PRE()                                                             \
    int tid = threadIdx.x, w = tid >> 6, lane = tid & 63;                      \
    int wm = w >> 2, wn = w & 3;                                               \
    int rloc = lane >> 3, clds = lane & 7, q = lane >> 4, l15 = lane & 15;     \
    floatx4 acc[4][4];                                                         \
    _Pragma("unroll")                                                          \
    for (int i = 0; i < 4; i++)                                                \
        _Pragma("unroll")                                                      \
        for (int j = 0; j < 4; j++) {                                          \
            floatx4 z = {0.f, 0.f, 0.f, 0.f}; acc[i][j] = z;                   \
        }

// ---- merged stage-A GEMM, 576 blocks, XCD-partitioned ----
// xcd = b&7, ws = b>>3 in [0,72): ws<40 routed (mt=5*xcd+ws/8, nt=ws&7, N-tile 256);
// else shared (mt = 2*xcd + s/16 in [0,16), nt = s&15 of 4096/256).
__global__ __launch_bounds__(512, 4) void gemm_A(
    const u16* __restrict__ XS, const u16* __restrict__ Xb,
    const u16* __restrict__ W13, const u16* __restrict__ S12,
    const float* __restrict__ b1, const float* __restrict__ b3,
    u16* __restrict__ H, u16* __restrict__ X3h, u16* __restrict__ G,
    const int* __restrict__ tileexp, const int* __restrict__ ntiles) {
    __shared__ u16 LDS[24576];
    int xcd = blockIdx.x & 7, ws = blockIdx.x >> 3;
    const u16 *Ab, *Bb; int mt, nt, e = 0; bool routed;
    if (ws < 40) {
        routed = true;
        mt = xcd * 5 + (ws >> 3);
        nt = ws & 7;
        if (mt >= ntiles[0]) return;
        e = tileexp[mt];
        Ab = XS; Bb = W13 + ((size_t)e << 21);
    } else {
        routed = false; int s = ws - 40;
        mt = xcd * 2 + (s >> 4);
        nt = s & 15;
        Ab = Xb; Bb = S12;
    }
    int m0 = mt * 128, n0 = nt * 256;
    GEMM_PRE();

    for (int k0 = 0; k0 < 1024; k0 += 64) {
        STAGE(Ab, Bb, 1024, k0);
        __syncthreads();
        COMPUTE();
        __syncthreads();
    }

    if (routed) {
#pragma unroll
        for (int i = 0; i < 4; i++) {
            int rowb = m0 + (wm << 6) + (i << 4) + (q << 2);
#pragma unroll
            for (int j = 0; j < 4; j++) {
                int col = n0 + (wn << 6) + (j << 4) + l15;
#pragma unroll
                for (int r = 0; r < 4; r++) {
                    float v = acc[i][j][r];
                    int rw = rowb + r;
                    if (nt < 4) {
                        H[(size_t)rw * 1024 + col] = f2bf(silu_f(v + b1[e * 1024 + col]));
                    } else {
                        int c2 = col - 1024;
                        X3h[(size_t)rw * 1024 + c2] = f2bf(v + b3[e * 1024 + c2]);
                    }
                }
            }
        }
    } else {
        // frag pair (jp, jp+1) = (u, v) of same logical col (S12 16-row interleave)
#pragma unroll
        for (int i = 0; i < 4; i++) {
            int rowb = m0 + (wm << 6) + (i << 4) + (q << 2);
#pragma unroll
            for (int jp = 0; jp < 4; jp += 2) {
                int brb = n0 + (wn << 6) + (jp << 4);
                int lcol = ((brb >> 5) << 4) + l15;
#pragma unroll
                for (int r = 0; r < 4; r++) {
                    float u = acc[i][jp][r], v = acc[i][jp + 1][r];
                    G[(size_t)(rowb + r) * 2048 + lcol] = f2bf(silu_f(u) * v);
                }
            }
        }
    }
}

// ---- merged stage-B GEMM, 448 blocks, split-K=2, XCD-partitioned ----
// ws<40 routed: mt=5*xcd+ws/8, nt=(ws&7)&3, kc=(ws&7)>>2 (K-chunk 512, 8 iters);
// else shared: mt=2*xcd+(s>>3), nt=(s&7)&3, kc=(s&7)>>2 (K-chunk 1024, 16 iters).
__global__ __launch_bounds__(512, 4) void gemm_B(
    const u16* __restrict__ H, const u16* __restrict__ G,
    const u16* __restrict__ W2b, const u16* __restrict__ S3b,
    const float* __restrict__ b2, const u16* __restrict__ X3h,
    u16* __restrict__ P0, u16* __restrict__ P1,
    float* __restrict__ Z0, float* __restrict__ Z1,
    const int* __restrict__ tileexp, const int* __restrict__ ntiles) {
    __shared__ u16 LDS[24576];
    int xcd = blockIdx.x & 7, ws = blockIdx.x >> 3;
    const u16 *Ab, *Bb; int mt, nt, kc, lda, kbeg, kend, e = 0; bool routed;
    if (ws < 40) {
        routed = true;
        mt = xcd * 5 + (ws >> 3);
        int r = ws & 7; nt = r & 3; kc = r >> 2;
        if (mt >= ntiles[0]) return;
        e = tileexp[mt];
        Ab = H; Bb = W2b + ((size_t)e << 20); lda = 1024; kbeg = kc << 9; kend = kbeg + 512;
    } else {
        routed = false; int s = ws - 40;
        mt = xcd * 2 + (s >> 3);
        int r = s & 7; nt = r & 3; kc = r >> 2;
        Ab = G; Bb = S3b; lda = 2048; kbeg = kc << 10; kend = kbeg + 1024;
    }
    int m0 = mt * 128, n0 = nt * 256;
    GEMM_PRE();

    for (int k0 = kbeg; k0 < kend; k0 += 64) {
        STAGE(Ab, Bb, lda, k0);
        __syncthreads();
        COMPUTE();
        __syncthreads();
    }

    if (routed) {
        u16* Pk = kc ? P1 : P0;
#pragma unroll
        for (int i = 0; i < 4; i++) {
            int rowb = m0 + (wm << 6) + (i << 4) + (q << 2);
#pragma unroll
            for (int j = 0; j < 4; j++) {
                int col = n0 + (wn << 6) + (j << 4) + l15;
#pragma unroll
                for (int r = 0; r < 4; r++) {
                    int rw = rowb + r;
                    float v = acc[i][j][r] + (kc == 0 ? b2[e * 1024 + col] : 0.f);
                    float pv = v * bf2f(X3h[(size_t)rw * 1024 + col]);
                    Pk[(size_t)rw * 1024 + col] = f2bf(pv);
                }
            }
        }
    } else {
        float* Zk = kc ? Z1 : Z0;
#pragma unroll
        for (int i = 0; i < 4; i++) {
            int rowb = m0 + (wm << 6) + (i << 4) + (q << 2);
#pragma unroll
            for (int j = 0; j < 4; j++) {
                int col = n0 + (wn << 6) + (j << 4) + l15;
#pragma unroll
                for (int r = 0; r < 4; r++)
                    Zk[(size_t)(rowb + r) * 1024 + col] = acc[i][j][r];
            }
        }
    }
}

__global__ void final_k(const float* __restrict__ Z0, const float* __restrict__ Z1,
                        const u16* __restrict__ P0, const u16* __restrict__ P1,
                        const int* __restrict__ slot_of, float* __restrict__ out) {
    int i = blockIdx.x * 256 + threadIdx.x;
    int t = i >> 8, c4 = i & 255;
    int s0 = slot_of[2 * t], s1 = slot_of[2 * t + 1];
    float4 z0 = ((const float4*)Z0)[(size_t)t * 256 + c4];
    float4 z1 = ((const float4*)Z1)[(size_t)t * 256 + c4];
    ushort4 a0 = ((const ushort4*)P0)[(size_t)s0 * 256 + c4];
    ushort4 a1 = ((const ushort4*)P1)[(size_t)s0 * 256 + c4];
    ushort4 c0 = ((const ushort4*)P0)[(size_t)s1 * 256 + c4];
    ushort4 c1 = ((const ushort4*)P1)[(size_t)s1 * 256 + c4];
    float4 o;
    o.x = z0.x + z1.x + bf2f(a0.x) + bf2f(a1.x) + bf2f(c0.x) + bf2f(c1.x);
    o.y = z0.y + z1.y + bf2f(a0.y) + bf2f(a1.y) + bf2f(c0.y) + bf2f(c1.y);
    o.z = z0.z + z1.z + bf2f(a0.z) + bf2f(a1.z) + bf2f(c0.z) + bf2f(c1.z);
    o.w = z0.w + z1.w + bf2f(a0.w) + bf2f(a1.w) + bf2f(c0.w) + bf2f(c1.w);
    ((float4*)out)[(size_t)t * 256 + c4] = o;
}

extern "C" void kernel_launch(void* const* d_in, const int* in_sizes, int n_in,
                              void* d_out, int out_size, void* d_ws, size_t ws_size,
                              hipStream_t stream) {
    const float* x   = (const float*)d_in[0];
    const float* gw  = (const float*)d_in[1];
    const float* w1  = (const float*)d_in[2];
    const float* b1  = (const float*)d_in[3];
    const float* w2  = (const float*)d_in[4];
    const float* b2  = (const float*)d_in[5];
    const float* w3  = (const float*)d_in[6];
    const float* b3  = (const float*)d_in[7];
    const float* sw1 = (const float*)d_in[8];
    const float* sw2 = (const float*)d_in[9];
    const float* sw3 = (const float*)d_in[10];
    float* out = (float*)d_out;

    char* p = (char*)d_ws;
    int* ntiles  = (int*)(p + 192);
    int* tileexp = (int*)(p + 256);
    size_t off = 4096;
    u16*   XS      = (u16*)(p + off);   off += (size_t)MAXROWS * 1024 * 2;
    int*   idxA    = (int*)(p + off);   off += 16384;
    float* wA      = (float*)(p + off); off += 16384;
    int*   slot_of = (int*)(p + off);   off += 16384;
    u16*   H       = (u16*)(p + off);   off += (size_t)MAXROWS * 1024 * 2;
    u16*   X3h     = (u16*)(p + off);   off += (size_t)MAXROWS * 1024 * 2;
    u16*   P0      = (u16*)(p + off);   off += (size_t)MAXROWS * 1024 * 2;
    u16*   P1      = (u16*)(p + off);   off += (size_t)MAXROWS * 1024 * 2;
    float* Z0      = (float*)(p + off); off += (size_t)2048 * 1024 * 4;
    float* Z1      = (float*)(p + off); off += (size_t)2048 * 1024 * 4;
    u16*   W13     = (u16*)(p + off);   off += (size_t)8 * 2048 * 1024 * 2;
    u16*   W2b     = (u16*)(p + off);   off += (size_t)8 * 1024 * 1024 * 2;
    u16*   S12     = (u16*)(p + off);   off += (size_t)4096 * 1024 * 2;
    u16*   S3b     = (u16*)(p + off);   off += (size_t)1024 * 2048 * 2;
    u16*   Xb      = (u16*)(p + off);   off += (size_t)2048 * 1024 * 2;
    u16*   G       = (u16*)(p + off);   off += (size_t)2048 * 2048 * 2;

    conv_gate<<<33280, 256, 0, stream>>>(w1, w2, w3, sw1, sw2, sw3, x, gw,
                                         W13, W2b, S12, S3b, Xb, idxA, wA);
    rank_k<<<1, 64, 0, stream>>>(idxA, tileexp, ntiles, slot_of);
    build_xs<<<4096, 256, 0, stream>>>(x, wA, slot_of, XS);

    gemm_A<<<576, 512, 0, stream>>>(XS, Xb, W13, S12, b1, b3, H, X3h, G,
                                    tileexp, ntiles);
    gemm_B<<<448, 512, 0, stream>>>(H, G, W2b, S3b, b2, X3h, P0, P1, Z0, Z1,
                                    tileexp, ntiles);
    final_k<<<2048, 256, 0, stream>>>(Z0, Z1, P0, P1, slot_of, out);
}